// Round 2
// baseline (796.322 us; speedup 1.0000x reference)
//
#include <hip/hip_runtime.h>
#include <math.h>

#define B_ 256
#define N_ 4096
#define D_ 128
#define C_ 32

typedef float vf4 __attribute__((ext_vector_type(4)));

// ---------------------------------------------------------------------------
// K0: precompute fw = softplus(feature_weights), wfw = fw * (-|distance_w|)
// ---------------------------------------------------------------------------
__global__ __launch_bounds__(256) void precompute_kernel(
    const float* __restrict__ fwin, const float* __restrict__ dwin,
    float* __restrict__ fw, float* __restrict__ wfw) {
  int i = blockIdx.x * 256 + threadIdx.x;
  if (i < N_ * D_) {
    float x = fwin[i];
    float sp = (x > 20.f) ? x : log1pf(expf(x));   // stable softplus
    float w  = -fabsf(dwin[i]);
    fw[i]  = sp;
    wfw[i] = sp * w;
  }
}

// ---------------------------------------------------------------------------
// K1: delta + activations. One 32-lane group per (b,n) row; 4 floats/lane.
// Grid: (B*N)/8 blocks of 256 threads (8 rows per block).
// ---------------------------------------------------------------------------
__global__ __launch_bounds__(256) void delta_act_kernel(
    const float* __restrict__ q,      // [B, D]
    const float* __restrict__ cases,  // [N, D]
    const float* __restrict__ fw,     // [N, D]
    const float* __restrict__ wfw,    // [N, D]
    const float* __restrict__ bias,   // [N]
    float* __restrict__ delta_out,    // [B, N, D]
    float* __restrict__ act_out) {    // [B, N]
  const int row  = blockIdx.x * 8 + (threadIdx.x >> 5);  // row = b*N + n
  const int lane = threadIdx.x & 31;
  const int b = row >> 12;          // N = 4096
  const int n = row & (N_ - 1);
  const int d0 = lane * 4;

  const vf4 qv = *(const vf4*)(q     + (size_t)b * D_ + d0);
  const vf4 cv = *(const vf4*)(cases + (size_t)n * D_ + d0);
  const vf4 fv = *(const vf4*)(fw    + (size_t)n * D_ + d0);
  const vf4 wv = *(const vf4*)(wfw   + (size_t)n * D_ + d0);

  vf4 dd = qv - cv;
  vf4 sq = dd * dd;
  vf4 dl = sq * fv;
  vf4 wa = sq * wv;

  float acc = wa.x + wa.y + wa.z + wa.w;

  __builtin_nontemporal_store(dl, (vf4*)(delta_out + (size_t)row * D_ + d0));

  // reduce across the 32-lane group
  #pragma unroll
  for (int off = 16; off > 0; off >>= 1)
    acc += __shfl_down(acc, off, 32);

  if (lane == 0) {
    float ca = acc + bias[n];
    act_out[row] = 1.f / (1.f + expf(-ca));
  }
}

// ---------------------------------------------------------------------------
// K2: per-b sum of activations -> inv[b] = 1/(sum + 0.01)
// ---------------------------------------------------------------------------
__global__ __launch_bounds__(256) void rowsum_kernel(
    const float* __restrict__ act, float* __restrict__ inv) {
  const int b = blockIdx.x;
  float s = 0.f;
  for (int n = threadIdx.x; n < N_; n += 256)
    s += act[(size_t)b * N_ + n];
  #pragma unroll
  for (int off = 32; off > 0; off >>= 1)
    s += __shfl_down(s, off, 64);
  __shared__ float sm[4];
  if ((threadIdx.x & 63) == 0) sm[threadIdx.x >> 6] = s;
  __syncthreads();
  if (threadIdx.x == 0) {
    float t = sm[0] + sm[1] + sm[2] + sm[3];
    inv[b] = 1.f / (t + 0.01f);
  }
}

// ---------------------------------------------------------------------------
// K3: y_hat[b,c] = inv[b] * sum_n act[b,n] * targets[n,c]
// One block per b; 32 c-lanes x 8 n-slices.
// ---------------------------------------------------------------------------
__global__ __launch_bounds__(256) void yhat_kernel(
    const float* __restrict__ act, const float* __restrict__ targets,
    const float* __restrict__ inv, float* __restrict__ y) {
  const int b = blockIdx.x;
  const int c = threadIdx.x & 31;
  const int g = threadIdx.x >> 5;
  float acc = 0.f;
  for (int n = g; n < N_; n += 8)
    acc += act[(size_t)b * N_ + n] * targets[(size_t)n * C_ + c];
  __shared__ float sm[8][32];
  sm[g][c] = acc;
  __syncthreads();
  if (g == 0) {
    float t = 0.f;
    #pragma unroll
    for (int k = 0; k < 8; k++) t += sm[k][c];
    y[(size_t)b * C_ + c] = t * inv[b];
  }
}

// ---------------------------------------------------------------------------
extern "C" void kernel_launch(void* const* d_in, const int* in_sizes, int n_in,
                              void* d_out, int out_size, void* d_ws, size_t ws_size,
                              hipStream_t stream) {
  const float* queries = (const float*)d_in[0];   // [B, D]
  const float* cases   = (const float*)d_in[1];   // [N, D]
  const float* targets = (const float*)d_in[2];   // [N, C]
  const float* fwin    = (const float*)d_in[3];   // [N, D]
  const float* dwin    = (const float*)d_in[4];   // [N, D]
  const float* bias    = (const float*)d_in[5];   // [N]

  float* out = (float*)d_out;
  float* y_hat = out;                              // [B, C]     8192
  float* act   = out + (size_t)B_ * C_;            // [B, N]     1048576
  float* delta = act + (size_t)B_ * N_;            // [B, N, D]  134217728

  float* fw  = (float*)d_ws;                       // [N, D]
  float* wfw = fw + (size_t)N_ * D_;               // [N, D]
  float* inv = wfw + (size_t)N_ * D_;               // [B]

  precompute_kernel<<<(N_ * D_) / 256, 256, 0, stream>>>(fwin, dwin, fw, wfw);

  delta_act_kernel<<<(B_ * N_) / 8, 256, 0, stream>>>(
      queries, cases, fw, wfw, bias, delta, act);

  rowsum_kernel<<<B_, 256, 0, stream>>>(act, inv);

  yhat_kernel<<<B_, 256, 0, stream>>>(act, targets, inv, y_hat);
}